// Round 4
// baseline (376.206 us; speedup 1.0000x reference)
//
#include <hip/hip_runtime.h>
#include <hip/hip_bf16.h>

typedef __hip_bfloat16 bf16;

#define B_   4
#define C_   32
#define DW_  64
#define H_   256
#define W_   256
#define P_   65536          // H_*W_
#define SRC_ 32             // source filter grid 32x32
#define PP_  66564          // padded plane 258*258

// ---- ws layout (float indices for the small stuff) ----
#define OW1    0            // 64*32
#define OB1    2048         // 64
#define OW3    2112         // 32*32
#define OB3    3136         // 32
#define OWS    3168         // 32*32 (sca)
#define OBS    4192         // 32
#define OW4    4224         // 64*32
#define OB4    6272         // 64
#define OW5    6336         // 32*32
#define OB5    7360         // 32
#define ON1W   7392
#define ON1B   7424
#define ON2W   7456
#define ON2B   7488
#define OBETA  7520
#define OGAMMA 7552
#define OSUMS  7584         // B_*C_ = 128
#define OSVEC  7712         // B_*C_ = 128
#define OFLAG  7900         // int flag: 0 = fp32 inputs, 1 = bf16 inputs
// byte offsets for big intermediates
#define CWF_BOFF 32768ull                        // cwf fp32: 4*64*9*1024*4 = 9437184 B
#define T1_BOFF  (CWF_BOFF + 9437184ull)         // t1 padded bf16: 256*66564*2 = 34080768 B
#define G_BOFF   (T1_BOFF + 34080768ull)         // g bf16: 16777216 B

__device__ __forceinline__ bf16  f2b(float v){ return __float2bfloat16(v); }
__device__ __forceinline__ float lo16(unsigned int u){ return __uint_as_float(u << 16); }
__device__ __forceinline__ float hi16(unsigned int u){ return __uint_as_float(u & 0xFFFF0000u); }
__device__ __forceinline__ unsigned short b2u(bf16 v){
    union { bf16 b; unsigned short u; } cv; cv.b = v; return cv.u;
}

template<typename T> __device__ __forceinline__ float ldf(const T* p);
template<> __device__ __forceinline__ float ldf<float>(const float* p){ return *p; }
template<> __device__ __forceinline__ float ldf<bf16>(const bf16* p){ return __bfloat162float(*p); }

template<typename T> __device__ __forceinline__ void stf(T* p, float v);
template<> __device__ __forceinline__ void stf<float>(float* p, float v){ *p = v; }
template<> __device__ __forceinline__ void stf<bf16>(bf16* p, float v){ *p = __float2bfloat16(v); }

// ---------------- dtype detector ----------------
__global__ void k_detect(const unsigned short* __restrict__ raw, int* __restrict__ flag)
{
    int t = threadIdx.x;  // 64 threads
    int bad = 0;
    for (int k = 0; k < 8; ++k) {
        unsigned short u = raw[2 * (t + 64 * k)];
        float v = __uint_as_float(((unsigned int)u) << 16);
        if (!(fabsf(v) < 1e6f)) bad = 1;
    }
    int anybad = __any(bad);
    if (t == 0) *flag = anybad ? 0 : 1;
}

// ---------------- weights -> fp32 in ws, zero SCA sums (unified) ----------------
template<typename T>
__device__ void prep_body(void* const* pp, float* wsf)
{
    int t = threadIdx.x;
    const T* w1 = (const T*)pp[0];  const T* b1 = (const T*)pp[1];
    const T* w3 = (const T*)pp[2];  const T* b3 = (const T*)pp[3];
    const T* wsc = (const T*)pp[4]; const T* bsc_ = (const T*)pp[5];
    const T* w4 = (const T*)pp[6];  const T* b4 = (const T*)pp[7];
    const T* w5 = (const T*)pp[8];  const T* b5 = (const T*)pp[9];
    const T* n1w = (const T*)pp[10]; const T* n1b = (const T*)pp[11];
    const T* n2w = (const T*)pp[12]; const T* n2b = (const T*)pp[13];
    const T* bet = (const T*)pp[14]; const T* gam = (const T*)pp[15];
    for (int i = t; i < 2048; i += 256) wsf[OW1 + i] = ldf<T>(w1 + i);
    for (int i = t; i < 64;   i += 256) wsf[OB1 + i] = ldf<T>(b1 + i);
    for (int i = t; i < 1024; i += 256) wsf[OW3 + i] = ldf<T>(w3 + i);
    for (int i = t; i < 32;   i += 256) wsf[OB3 + i] = ldf<T>(b3 + i);
    for (int i = t; i < 1024; i += 256) wsf[OWS + i] = ldf<T>(wsc + i);
    for (int i = t; i < 32;   i += 256) wsf[OBS + i] = ldf<T>(bsc_ + i);
    for (int i = t; i < 2048; i += 256) wsf[OW4 + i] = ldf<T>(w4 + i);
    for (int i = t; i < 64;   i += 256) wsf[OB4 + i] = ldf<T>(b4 + i);
    for (int i = t; i < 1024; i += 256) wsf[OW5 + i] = ldf<T>(w5 + i);
    for (int i = t; i < 32;   i += 256) wsf[OB5 + i] = ldf<T>(b5 + i);
    for (int i = t; i < 32;   i += 256) wsf[ON1W + i] = ldf<T>(n1w + i);
    for (int i = t; i < 32;   i += 256) wsf[ON1B + i] = ldf<T>(n1b + i);
    for (int i = t; i < 32;   i += 256) wsf[ON2W + i] = ldf<T>(n2w + i);
    for (int i = t; i < 32;   i += 256) wsf[ON2B + i] = ldf<T>(n2b + i);
    for (int i = t; i < 32;   i += 256) wsf[OBETA + i] = ldf<T>(bet + i);
    for (int i = t; i < 32;   i += 256) wsf[OGAMMA + i] = ldf<T>(gam + i);
    for (int i = t; i < 128;  i += 256) wsf[OSUMS + i] = 0.f;
}

__global__ void k_prep(const void* p0, const void* p1, const void* p2, const void* p3,
                       const void* p4, const void* p5, const void* p6, const void* p7,
                       const void* p8, const void* p9, const void* p10, const void* p11,
                       const void* p12, const void* p13, const void* p14, const void* p15,
                       float* __restrict__ wsf, const int* __restrict__ flag)
{
    const void* pp[16] = {p0,p1,p2,p3,p4,p5,p6,p7,p8,p9,p10,p11,p12,p13,p14,p15};
    if (*flag == 0) prep_body<float>((void* const*)pp, wsf);
    else            prep_body<bf16>((void* const*)pp, wsf);
}

// ---------------- cw2 bf16 -> fp32 (only needed on bf16 path) ----------------
__global__ void k_cwf(const void* __restrict__ cw, float* __restrict__ cwf,
                      const int* __restrict__ flag)
{
    if (*flag == 0) return;   // fp32 path: k_ddf reads d_in[1] directly
    const bf16* c = (const bf16*)cw;
    int i0 = blockIdx.x * 256 + threadIdx.x;
    const int n = B_ * DW_ * 9 * 1024;
    for (int i = i0; i < n; i += 262144) cwf[i] = __bfloat162float(c[i]);
}

// ---------------- zero the padded borders of t1 ----------------
__global__ void k_zpad(unsigned short* __restrict__ t1u)
{
    unsigned short* pl = t1u + (size_t)blockIdx.x * PP_;   // 256 planes
    int t = threadIdx.x;
    for (int i = t; i < 258; i += 256) {
        pl[i] = 0;
        pl[257 * 258 + i] = 0;
    }
    pl[(t + 1) * 258] = 0;
    pl[(t + 1) * 258 + 257] = 0;
}

// ---------------- LayerNorm2d + conv1 (32->64), writes padded t1 ----------------
template<typename T>
__device__ void ln1_body(const T* __restrict__ inp, const float* __restrict__ wsf,
                         bf16* __restrict__ t1p)
{
    int tid = blockIdx.x * 256 + threadIdx.x;
    int b = tid >> 16;
    int p = tid & 65535;
    int h = p >> 8, w = p & 255;
    const T* ip = inp + (size_t)b * C_ * P_ + p;
    float v[C_];
    float m = 0.f;
    #pragma unroll
    for (int ch = 0; ch < C_; ++ch) { v[ch] = ldf<T>(ip + ch * P_); m += v[ch]; }
    m *= (1.f / C_);
    float var = 0.f;
    #pragma unroll
    for (int ch = 0; ch < C_; ++ch) { float d = v[ch] - m; var += d * d; }
    var *= (1.f / C_);
    float inv = rsqrtf(var + 1e-6f);
    #pragma unroll
    for (int ch = 0; ch < C_; ++ch)
        v[ch] = (v[ch] - m) * inv * wsf[ON1W + ch] + wsf[ON1B + ch];

    bf16* op = t1p + (size_t)(b * DW_) * PP_ + (h + 1) * 258 + (w + 1);
    #pragma unroll 4
    for (int o = 0; o < DW_; ++o) {
        float acc = wsf[OB1 + o];
        #pragma unroll
        for (int ch = 0; ch < C_; ++ch) acc += v[ch] * wsf[OW1 + o * C_ + ch];
        op[(size_t)o * PP_] = f2b(acc);
    }
}

__global__ __launch_bounds__(256) void k_ln1(const void* __restrict__ inp,
        const float* __restrict__ wsf, bf16* __restrict__ t1p,
        const int* __restrict__ flag)
{
    if (*flag == 0) ln1_body<float>((const float*)inp, wsf, t1p);
    else            ln1_body<bf16>((const bf16*)inp, wsf, t1p);
}

// ------ DDF v3: 2x2 px/thread, waves split channels, 4-corner bilinear ------
// block = 256 threads = 4 waves, covers 16x16 px; wave w does cp in [8w,8w+8).
__global__ __launch_bounds__(256, 4) void k_ddf(const unsigned short* __restrict__ t1u,
        const float* __restrict__ cwf, const float* __restrict__ cwraw,
        bf16* __restrict__ g, float* __restrict__ sums, const int* __restrict__ flag)
{
    __shared__ float V4[9216];   // [pt=ch*9+tap][4 rows][4 cols], 36 KB

    const float* csel = (*flag == 0) ? cwraw : cwf;

    int bid = blockIdx.x;
    int b = bid >> 8;
    int tb = bid & 255;
    int bch = (tb >> 4) * 2;     // block's base cell row (2x2 cells)
    int bcw = (tb & 15) * 2;

    // --- stage 4x4 corner region for all 576 planes ---
    {
        const float* cb = csel + (size_t)b * (DW_ * 9 * 1024);
        int rof[4], cof[4];
        #pragma unroll
        for (int k = 0; k < 4; ++k) {
            int rr = bch - 1 + k; rr = rr < 0 ? 0 : (rr > 31 ? 31 : rr);
            int cc = bcw - 1 + k; cc = cc < 0 ? 0 : (cc > 31 ? 31 : cc);
            rof[k] = rr * SRC_; cof[k] = cc;
        }
        for (int it = 0; it < 36; ++it) {
            int idx = it * 256 + threadIdx.x;        // 0..9215
            int cc = idx & 3, rr = (idx >> 2) & 3, pt = idx >> 4;
            V4[idx] = cb[pt * 1024 + rof[rr] + cof[cc]];
        }
    }
    __syncthreads();

    int wid = threadIdx.x >> 6, lane = threadIdx.x & 63;
    int cell_r = lane >> 5;             // 0..1
    int cell_c = (lane >> 4) & 1;       // 0..1
    int tr = (lane >> 2) & 3;           // 0..3  (2x2 px tile row within cell)
    int tc = lane & 3;

    int kt = cell_r + (tr >> 1);        // top corner row in staged 4x4
    int kl = cell_c + (tc >> 1);        // left corner col
    int h0 = (bch + cell_r) * 8 + 2 * tr;
    int w0 = (bcw + cell_c) * 8 + 2 * tc;

    // bilinear fractional weights per pixel (r = 2tr+dr within cell)
    float fh0 = (2 * tr) * 0.125f + ((tr < 2) ? 0.5625f : -0.4375f);
    float fh1 = fh0 + 0.125f;
    float fw0 = (2 * tc) * 0.125f + ((tc < 2) ? 0.5625f : -0.4375f);
    float fw1 = fw0 + 0.125f;
    float aw[2][2][4];
    #pragma unroll
    for (int dr = 0; dr < 2; ++dr) {
        float fh = dr ? fh1 : fh0;
        #pragma unroll
        for (int dc = 0; dc < 2; ++dc) {
            float fw = dc ? fw1 : fw0;
            aw[dr][dc][0] = (1.f - fh) * (1.f - fw);
            aw[dr][dc][1] = (1.f - fh) * fw;
            aw[dr][dc][2] = fh * (1.f - fw);
            aw[dr][dc][3] = fh * fw;
        }
    }

    int cp0 = wid * 8;
    for (int cl = 0; cl < 8; ++cl) {
        int cp = cp0 + cl;
        // --- load 4x4 t1 patches for both halves (u32 pairs, 4B-aligned) ---
        float P1[4][4], P2[4][4];
        const unsigned short* pl1 = t1u + (size_t)(b * DW_ + cp) * PP_ + h0 * 258 + w0;
        const unsigned short* pl2 = pl1 + (size_t)C_ * PP_;
        #pragma unroll
        for (int rr = 0; rr < 4; ++rr) {
            const unsigned int* rp1 = (const unsigned int*)(pl1 + rr * 258);
            unsigned int u0 = rp1[0], u1 = rp1[1];
            P1[rr][0] = lo16(u0); P1[rr][1] = hi16(u0);
            P1[rr][2] = lo16(u1); P1[rr][3] = hi16(u1);
            const unsigned int* rp2 = (const unsigned int*)(pl2 + rr * 258);
            u0 = rp2[0]; u1 = rp2[1];
            P2[rr][0] = lo16(u0); P2[rr][1] = hi16(u0);
            P2[rr][2] = lo16(u1); P2[rr][3] = hi16(u1);
        }

        float acc1[2][2] = {{0.f,0.f},{0.f,0.f}};
        float acc2[2][2] = {{0.f,0.f},{0.f,0.f}};
        const float* q1 = &V4[(cp * 9) * 16 + kt * 4 + kl];
        const float* q2 = &V4[((cp + 32) * 9) * 16 + kt * 4 + kl];
        #pragma unroll
        for (int i = 0; i < 3; ++i) {
            #pragma unroll
            for (int j = 0; j < 3; ++j) {
                int tap = (i * 3 + j) * 16;
                float t00 = q1[tap], t01 = q1[tap + 1], t10 = q1[tap + 4], t11 = q1[tap + 5];
                float s00 = q2[tap], s01 = q2[tap + 1], s10 = q2[tap + 4], s11 = q2[tap + 5];
                #pragma unroll
                for (int dr = 0; dr < 2; ++dr) {
                    #pragma unroll
                    for (int dc = 0; dc < 2; ++dc) {
                        float f1 = aw[dr][dc][0] * t00 + aw[dr][dc][1] * t01
                                 + aw[dr][dc][2] * t10 + aw[dr][dc][3] * t11;
                        float f2 = aw[dr][dc][0] * s00 + aw[dr][dc][1] * s01
                                 + aw[dr][dc][2] * s10 + aw[dr][dc][3] * s11;
                        acc1[dr][dc] += P1[dr + i][dc + j] * f1;
                        acc2[dr][dc] += P2[dr + i][dc + j] * f2;
                    }
                }
            }
        }

        // gate, pack-store 2 px per u32, SCA partial sum
        float g00 = acc1[0][0] * acc2[0][0];
        float g01 = acc1[0][1] * acc2[0][1];
        float g10 = acc1[1][0] * acc2[1][0];
        float g11 = acc1[1][1] * acc2[1][1];
        unsigned int* gp = (unsigned int*)(g + (size_t)(b * C_ + cp) * P_ + h0 * 256 + w0);
        gp[0]   = ((unsigned int)b2u(f2b(g01)) << 16) | b2u(f2b(g00));
        gp[128] = ((unsigned int)b2u(f2b(g11)) << 16) | b2u(f2b(g10));   // next row: 256 els = 128 u32

        float s = g00 + g01 + g10 + g11;
        #pragma unroll
        for (int off = 32; off >= 1; off >>= 1) s += __shfl_xor(s, off, 64);
        if (lane == 0) atomicAdd(&sums[b * C_ + cp], s);
    }
}

// ---------------- SCA vector: s = sca_w @ mean + sca_b ----------------
__global__ void k_sca(float* __restrict__ wsf)
{
    int t = threadIdx.x;            // 128 threads
    int b = t >> 5, o = t & 31;
    float acc = wsf[OBS + o];
    #pragma unroll
    for (int ch = 0; ch < C_; ++ch)
        acc += wsf[OWS + o * C_ + ch] * (wsf[OSUMS + b * C_ + ch] * (1.f / (float)P_));
    wsf[OSVEC + b * C_ + o] = acc;
}

// ------- tail: scale, conv3, +beta residual, LN2, conv4, gate, conv5, out -------
template<typename T>
__device__ void tail_body(const T* __restrict__ inp, const bf16* __restrict__ g,
                          const float* __restrict__ wsf, T* __restrict__ out)
{
    int tid = blockIdx.x * 256 + threadIdx.x;
    int b = tid >> 16;
    int p = tid & 65535;
    const bf16* gp = g + (size_t)b * C_ * P_ + p;
    const T* ip = inp + (size_t)b * C_ * P_ + p;

    float x[C_];
    #pragma unroll
    for (int ch = 0; ch < C_; ++ch)
        x[ch] = __bfloat162float(gp[ch * P_]) * wsf[OSVEC + b * C_ + ch];

    float y[C_];
    #pragma unroll 4
    for (int o = 0; o < C_; ++o) {
        float acc = wsf[OB3 + o];
        #pragma unroll
        for (int ch = 0; ch < C_; ++ch) acc += x[ch] * wsf[OW3 + o * C_ + ch];
        y[o] = ldf<T>(ip + o * P_) + acc * wsf[OBETA + o];
    }

    float m = 0.f;
    #pragma unroll
    for (int ch = 0; ch < C_; ++ch) m += y[ch];
    m *= (1.f / C_);
    float var = 0.f;
    #pragma unroll
    for (int ch = 0; ch < C_; ++ch) { float d = y[ch] - m; var += d * d; }
    var *= (1.f / C_);
    float inv = rsqrtf(var + 1e-6f);
    float yn[C_];
    #pragma unroll
    for (int ch = 0; ch < C_; ++ch)
        yn[ch] = (y[ch] - m) * inv * wsf[ON2W + ch] + wsf[ON2B + ch];

    float u[C_];
    #pragma unroll 2
    for (int o = 0; o < C_; ++o) {
        float a = wsf[OB4 + o], bb = wsf[OB4 + 32 + o];
        #pragma unroll
        for (int ch = 0; ch < C_; ++ch) {
            a  += yn[ch] * wsf[OW4 + o * C_ + ch];
            bb += yn[ch] * wsf[OW4 + (o + 32) * C_ + ch];
        }
        u[o] = a * bb;
    }

    T* op = out + (size_t)b * C_ * P_ + p;
    #pragma unroll 4
    for (int o = 0; o < C_; ++o) {
        float acc = wsf[OB5 + o];
        #pragma unroll
        for (int ch = 0; ch < C_; ++ch) acc += u[ch] * wsf[OW5 + o * C_ + ch];
        stf<T>(op + o * P_, y[o] + acc * wsf[OGAMMA + o]);
    }
}

__global__ __launch_bounds__(256) void k_tail(const void* __restrict__ inp,
        const bf16* __restrict__ g, const float* __restrict__ wsf,
        void* __restrict__ out, const int* __restrict__ flag)
{
    if (*flag == 0) tail_body<float>((const float*)inp, g, wsf, (float*)out);
    else            tail_body<bf16>((const bf16*)inp, g, wsf, (bf16*)out);
}

extern "C" void kernel_launch(void* const* d_in, const int* in_sizes, int n_in,
                              void* d_out, int out_size, void* d_ws, size_t ws_size,
                              hipStream_t stream)
{
    float* wsf = (float*)d_ws;
    char* wsb = (char*)d_ws;
    float* cwf = (float*)(wsb + CWF_BOFF);
    bf16* t1p = (bf16*)(wsb + T1_BOFF);
    bf16* g   = (bf16*)(wsb + G_BOFF);
    int* flag = (int*)(wsf + OFLAG);

    k_detect<<<1, 64, 0, stream>>>((const unsigned short*)d_in[0], flag);

    k_prep<<<1, 256, 0, stream>>>(d_in[2], d_in[3], d_in[4], d_in[5], d_in[6], d_in[7],
                                  d_in[8], d_in[9], d_in[10], d_in[11], d_in[12], d_in[13],
                                  d_in[14], d_in[15], d_in[16], d_in[17], wsf, flag);
    k_cwf<<<1024, 256, 0, stream>>>(d_in[1], cwf, flag);
    k_zpad<<<256, 256, 0, stream>>>((unsigned short*)t1p);

    int nblk = (B_ * P_) / 256;   // 1024
    k_ln1<<<nblk, 256, 0, stream>>>(d_in[0], wsf, t1p, flag);

    k_ddf<<<1024, 256, 0, stream>>>((const unsigned short*)t1p, cwf,
                                    (const float*)d_in[1], g, wsf + OSUMS, flag);

    k_sca<<<1, 128, 0, stream>>>(wsf);

    k_tail<<<nblk, 256, 0, stream>>>(d_in[0], g, wsf, d_out, flag);
}

// Round 5
// 364.766 us; speedup vs baseline: 1.0314x; 1.0314x over previous
//
#include <hip/hip_runtime.h>
#include <hip/hip_bf16.h>

typedef __hip_bfloat16 bf16;

#define B_   4
#define C_   32
#define DW_  64
#define H_   256
#define W_   256
#define P_   65536
#define SRC_ 32
#define PPU_ 66564          // padded pair-plane, u32 elements (258*258)
#define PSTR_ 258

// ---- ws float-index offsets (small region) ----
#define OW1    0
#define OB1    2048
#define OW3    2112
#define OB3    3136
#define OWS    3168
#define OBS    4192
#define OW4    4224
#define OB4    6272
#define OW5    6336
#define OB5    7360
#define ON1W   7392
#define ON1B   7424
#define ON2W   7456
#define ON2B   7488
#define OBETA  7520
#define OGAMMA 7552
#define OSUMS  7584
#define OSVEC  7712
#define OFLAG  7900
// u32-index offsets for bf16-packed tail weights
#define OPK3u  8192         // 512 u32
#define OPK4u  8704         // 1024 u32
#define OPK5u  9728         // 512 u32  (ends 10240 -> byte 40960)
// byte offsets
#define CWF_BOFF 40960ull                        // 9437184 B
#define T1_BOFF  (CWF_BOFF + 9437184ull)         // paired padded: 128*66564*4 = 34080768 B
#define G_BOFF   (T1_BOFF + 34080768ull)         // g bf16: 16777216 B -> end ~60.3 MB

__device__ __forceinline__ float lo16f(unsigned u){ return __uint_as_float(u << 16); }
__device__ __forceinline__ float hi16f(unsigned u){ return __uint_as_float(u & 0xFFFF0000u); }
__device__ __forceinline__ unsigned short bbits(float v){
    union { bf16 b; unsigned short u; } cv; cv.b = __float2bfloat16(v); return cv.u;
}
__device__ __forceinline__ unsigned pkf(float lo, float hi){
    return ((unsigned)bbits(hi) << 16) | bbits(lo);
}

template<typename T> __device__ __forceinline__ float ldf(const T* p);
template<> __device__ __forceinline__ float ldf<float>(const float* p){ return *p; }
template<> __device__ __forceinline__ float ldf<bf16>(const bf16* p){ return __bfloat162float(*p); }

// ---------------- k_setup: flag + weight prep + packs + cwf + zpad ----------------
template<typename T>
__device__ void prep_body(const void* const* pp, float* wsf, unsigned* wsu)
{
    int t = threadIdx.x;
    const T* w3 = (const T*)pp[2];  const T* w4 = (const T*)pp[6];
    const T* w5 = (const T*)pp[8];
    {
        const T* w1 = (const T*)pp[0];
        for (int i = t; i < 2048; i += 256) wsf[OW1 + i] = ldf<T>(w1 + i);
    }
    for (int i = t; i < 64;   i += 256) wsf[OB1 + i] = ldf<T>((const T*)pp[1] + i);
    for (int i = t; i < 1024; i += 256) wsf[OW3 + i] = ldf<T>(w3 + i);
    for (int i = t; i < 32;   i += 256) wsf[OB3 + i] = ldf<T>((const T*)pp[3] + i);
    for (int i = t; i < 1024; i += 256) wsf[OWS + i] = ldf<T>((const T*)pp[4] + i);
    for (int i = t; i < 32;   i += 256) wsf[OBS + i] = ldf<T>((const T*)pp[5] + i);
    for (int i = t; i < 2048; i += 256) wsf[OW4 + i] = ldf<T>(w4 + i);
    for (int i = t; i < 64;   i += 256) wsf[OB4 + i] = ldf<T>((const T*)pp[7] + i);
    for (int i = t; i < 1024; i += 256) wsf[OW5 + i] = ldf<T>(w5 + i);
    for (int i = t; i < 32;   i += 256) wsf[OB5 + i] = ldf<T>((const T*)pp[9] + i);
    for (int i = t; i < 32;   i += 256) wsf[ON1W + i] = ldf<T>((const T*)pp[10] + i);
    for (int i = t; i < 32;   i += 256) wsf[ON1B + i] = ldf<T>((const T*)pp[11] + i);
    for (int i = t; i < 32;   i += 256) wsf[ON2W + i] = ldf<T>((const T*)pp[12] + i);
    for (int i = t; i < 32;   i += 256) wsf[ON2B + i] = ldf<T>((const T*)pp[13] + i);
    for (int i = t; i < 32;   i += 256) wsf[OBETA + i] = ldf<T>((const T*)pp[14] + i);
    for (int i = t; i < 32;   i += 256) wsf[OGAMMA + i] = ldf<T>((const T*)pp[15] + i);
    for (int i = t; i < 128;  i += 256) wsf[OSUMS + i] = 0.f;
    // bf16-packed tail weights (pairs along in-ch)
    for (int i = t; i < 512; i += 256) {
        int o = i >> 4, c = (i & 15) * 2;
        wsu[OPK3u + i] = pkf(ldf<T>(w3 + o*32 + c), ldf<T>(w3 + o*32 + c + 1));
        wsu[OPK5u + i] = pkf(ldf<T>(w5 + o*32 + c), ldf<T>(w5 + o*32 + c + 1));
    }
    for (int i = t; i < 1024; i += 256) {
        int o = i >> 4, c = (i & 15) * 2;
        wsu[OPK4u + i] = pkf(ldf<T>(w4 + o*32 + c), ldf<T>(w4 + o*32 + c + 1));
    }
}

__global__ __launch_bounds__(256) void k_setup(
    const unsigned short* __restrict__ raw, const void* __restrict__ cw,
    const void* p2, const void* p3, const void* p4, const void* p5,
    const void* p6, const void* p7, const void* p8, const void* p9,
    const void* p10, const void* p11, const void* p12, const void* p13,
    const void* p14, const void* p15, const void* p16, const void* p17,
    float* __restrict__ wsf, unsigned* __restrict__ wsu,
    float* __restrict__ cwf, unsigned* __restrict__ t1u, int* __restrict__ flagp)
{
    __shared__ int sbad;
    if (threadIdx.x == 0) sbad = 0;
    __syncthreads();
    int bad = 0;
    for (int k = 0; k < 8; ++k) {
        unsigned short u = raw[2 * (threadIdx.x * 8 + k)];
        float v = __uint_as_float(((unsigned)u) << 16);
        if (!(fabsf(v) < 1e6f)) bad = 1;
    }
    if (bad) sbad = 1;
    __syncthreads();
    int flag = sbad ? 0 : 1;

    int bid = blockIdx.x;
    if (bid == 0) {
        const void* pp[16] = {p2,p3,p4,p5,p6,p7,p8,p9,p10,p11,p12,p13,p14,p15,p16,p17};
        if (flag == 0) prep_body<float>(pp, wsf, wsu);
        else           prep_body<bf16>(pp, wsf, wsu);
        if (threadIdx.x == 0) *flagp = flag;
    }
    if (bid < 128) {   // zero padded borders of the 128 pair-planes
        unsigned* pl = t1u + (size_t)bid * PPU_;
        for (int i = threadIdx.x; i < 258; i += 256) { pl[i] = 0; pl[257*258 + i] = 0; }
        int r = threadIdx.x + 1;   // 1..256
        pl[r * 258] = 0; pl[r * 258 + 257] = 0;
    }
    if (flag == 1) {   // cw2 bf16 -> fp32 linear copy
        const bf16* c = (const bf16*)cw;
        int base = bid * 2304;
        for (int i = threadIdx.x; i < 2304; i += 256)
            cwf[base + i] = __bfloat162float(c[base + i]);
    }
}

// ---------------- float4 helpers ----------------
__device__ __forceinline__ float4 f4set(float v){ return make_float4(v,v,v,v); }
__device__ __forceinline__ float4 fma4s(float4 v, float w, float4 a){
    a.x += v.x*w; a.y += v.y*w; a.z += v.z*w; a.w += v.w*w; return a;
}

// ---------------- k_ln1: LN + conv1, 4 px/thread, paired padded t1 out ----------------
__global__ __launch_bounds__(256) void k_ln1(const void* __restrict__ inp_,
        const float* __restrict__ wsf, unsigned* __restrict__ t1u,
        const int* __restrict__ flag)
{
    __shared__ float LW[2176];   // W1 2048 | b1 64 | n1w 32 | n1b 32
    for (int i = threadIdx.x; i < 2048; i += 256) LW[i] = wsf[OW1 + i];
    if (threadIdx.x < 64) LW[2048 + threadIdx.x] = wsf[OB1 + threadIdx.x];
    if (threadIdx.x < 32) { LW[2112 + threadIdx.x] = wsf[ON1W + threadIdx.x];
                            LW[2144 + threadIdx.x] = wsf[ON1B + threadIdx.x]; }
    __syncthreads();

    int b = blockIdx.x >> 6;
    int po = (blockIdx.x & 63) * 1024 + threadIdx.x * 4;
    int h = po >> 8, w = po & 255;
    bool isf = (*flag == 0);

    float4 v[32];
    if (isf) {
        const float* ip = (const float*)inp_ + (size_t)b * C_ * P_ + po;
        #pragma unroll
        for (int ch = 0; ch < 32; ++ch) v[ch] = *(const float4*)(ip + ch * P_);
    } else {
        const unsigned short* ip = (const unsigned short*)inp_ + (size_t)b * C_ * P_ + po;
        #pragma unroll
        for (int ch = 0; ch < 32; ++ch) {
            uint2 u = *(const uint2*)(ip + ch * P_);
            v[ch] = make_float4(lo16f(u.x), hi16f(u.x), lo16f(u.y), hi16f(u.y));
        }
    }
    float4 m = f4set(0.f);
    #pragma unroll
    for (int ch = 0; ch < 32; ++ch) { m.x += v[ch].x; m.y += v[ch].y; m.z += v[ch].z; m.w += v[ch].w; }
    m.x *= (1.f/32); m.y *= (1.f/32); m.z *= (1.f/32); m.w *= (1.f/32);
    float4 var = f4set(0.f);
    #pragma unroll
    for (int ch = 0; ch < 32; ++ch) {
        float dx=v[ch].x-m.x, dy=v[ch].y-m.y, dz=v[ch].z-m.z, dw=v[ch].w-m.w;
        var.x += dx*dx; var.y += dy*dy; var.z += dz*dz; var.w += dw*dw;
    }
    float4 inv = make_float4(rsqrtf(var.x*(1.f/32)+1e-6f), rsqrtf(var.y*(1.f/32)+1e-6f),
                             rsqrtf(var.z*(1.f/32)+1e-6f), rsqrtf(var.w*(1.f/32)+1e-6f));
    #pragma unroll
    for (int ch = 0; ch < 32; ++ch) {
        float g = LW[2112+ch], bb = LW[2144+ch];
        v[ch].x = (v[ch].x-m.x)*inv.x*g + bb;
        v[ch].y = (v[ch].y-m.y)*inv.y*g + bb;
        v[ch].z = (v[ch].z-m.z)*inv.z*g + bb;
        v[ch].w = (v[ch].w-m.w)*inv.w*g + bb;
    }

    const float4* W4p = (const float4*)LW;
    #pragma unroll 2
    for (int o = 0; o < 32; ++o) {
        float4 a = f4set(LW[2048 + o]);
        float4 c = f4set(LW[2048 + 32 + o]);
        #pragma unroll
        for (int k = 0; k < 8; ++k) {
            float4 wa = W4p[o*8 + k];
            float4 wb = W4p[(o+32)*8 + k];
            float4 v0 = v[4*k], v1 = v[4*k+1], v2 = v[4*k+2], v3 = v[4*k+3];
            a = fma4s(v0, wa.x, a); a = fma4s(v1, wa.y, a);
            a = fma4s(v2, wa.z, a); a = fma4s(v3, wa.w, a);
            c = fma4s(v0, wb.x, c); c = fma4s(v1, wb.y, c);
            c = fma4s(v2, wb.z, c); c = fma4s(v3, wb.w, c);
        }
        unsigned* dst = t1u + (size_t)(b*32 + o) * PPU_ + (h+1)*PSTR_ + (w+1);
        dst[0] = pkf(a.x, c.x); dst[1] = pkf(a.y, c.y);
        dst[2] = pkf(a.z, c.z); dst[3] = pkf(a.w, c.w);
    }
}

// ---------------- k_ddf: 2x2 px/thread, paired t1, paired LDS corners ----------------
__global__ __launch_bounds__(256) void k_ddf(const unsigned* __restrict__ t1u,
        const float* __restrict__ cwf, const float* __restrict__ cwraw,
        unsigned* __restrict__ g32, float* __restrict__ sums,
        const int* __restrict__ flag)
{
    __shared__ float V[9216];   // [q=cp*9+tap][rr 0..3][cc 0..3][half 0..1]

    const float* csel = (*flag == 0) ? cwraw : cwf;
    int bid = blockIdx.x;
    int b = bid >> 8;
    int tb = bid & 255;
    int bch = (tb >> 4) * 2, bcw = (tb & 15) * 2;

    const float* cb = csel + (size_t)b * (DW_*9*1024);
    for (int idx = threadIdx.x; idx < 1152; idx += 256) {
        int q = idx >> 2, rr = idx & 3;
        int srow = bch - 1 + rr; srow = srow < 0 ? 0 : (srow > 31 ? 31 : srow);
        const float* s0 = cb + q*1024 + srow*32;
        const float* s1 = s0 + 288*1024;
        float fo[8];
        #pragma unroll
        for (int cc = 0; cc < 4; ++cc) {
            int col = bcw - 1 + cc; col = col < 0 ? 0 : (col > 31 ? 31 : col);
            fo[2*cc]   = s0[col];
            fo[2*cc+1] = s1[col];
        }
        float* dst = &V[(q*16 + rr*4) * 2];
        *(float4*)dst       = make_float4(fo[0],fo[1],fo[2],fo[3]);
        *(float4*)(dst + 4) = make_float4(fo[4],fo[5],fo[6],fo[7]);
    }
    __syncthreads();

    int wid = threadIdx.x >> 6, lane = threadIdx.x & 63;
    int cell_r = lane >> 5, cell_c = (lane >> 4) & 1;
    int tr = (lane >> 2) & 3, tc = lane & 3;
    int kt = cell_r + (tr >> 1), kl = cell_c + (tc >> 1);
    int h0 = (bch + cell_r)*8 + 2*tr;
    int w0 = (bcw + cell_c)*8 + 2*tc;

    float fh0 = (2*tr)*0.125f + ((tr < 2) ? 0.5625f : -0.4375f);
    float fh1 = fh0 + 0.125f;
    float fw0 = (2*tc)*0.125f + ((tc < 2) ? 0.5625f : -0.4375f);
    float fw1 = fw0 + 0.125f;
    float aw[2][2][4];
    #pragma unroll
    for (int dr = 0; dr < 2; ++dr) {
        float fh = dr ? fh1 : fh0;
        #pragma unroll
        for (int dc = 0; dc < 2; ++dc) {
            float fw = dc ? fw1 : fw0;
            aw[dr][dc][0] = (1.f-fh)*(1.f-fw);
            aw[dr][dc][1] = (1.f-fh)*fw;
            aw[dr][dc][2] = fh*(1.f-fw);
            aw[dr][dc][3] = fh*fw;
        }
    }

    int tbase = h0 * PSTR_ + w0;   // storage row h0 == px row h0-1 (pad shift)
    for (int cl = 0; cl < 8; ++cl) {
        int cp = wid*8 + cl;
        const unsigned* tp = t1u + (size_t)(b*32 + cp) * PPU_ + tbase;
        float P1[4][4], P2[4][4];
        #pragma unroll
        for (int rr = 0; rr < 4; ++rr) {
            uint2 ua = *(const uint2*)(tp + rr*PSTR_);
            uint2 ub = *(const uint2*)(tp + rr*PSTR_ + 2);
            P1[rr][0] = lo16f(ua.x); P2[rr][0] = hi16f(ua.x);
            P1[rr][1] = lo16f(ua.y); P2[rr][1] = hi16f(ua.y);
            P1[rr][2] = lo16f(ub.x); P2[rr][2] = hi16f(ub.x);
            P1[rr][3] = lo16f(ub.y); P2[rr][3] = hi16f(ub.y);
        }

        float acc1[2][2] = {{0.f,0.f},{0.f,0.f}};
        float acc2[2][2] = {{0.f,0.f},{0.f,0.f}};
        const float* q1 = &V[(cp*9)*32 + (kt*4 + kl)*2];
        #pragma unroll
        for (int i = 0; i < 3; ++i) {
            #pragma unroll
            for (int j = 0; j < 3; ++j) {
                int toff = (i*3 + j) * 32;
                float2 c00 = *(const float2*)(q1 + toff);
                float2 c01 = *(const float2*)(q1 + toff + 2);
                float2 c10 = *(const float2*)(q1 + toff + 8);
                float2 c11 = *(const float2*)(q1 + toff + 10);
                #pragma unroll
                for (int dr = 0; dr < 2; ++dr) {
                    #pragma unroll
                    for (int dc = 0; dc < 2; ++dc) {
                        float f1 = aw[dr][dc][0]*c00.x + aw[dr][dc][1]*c01.x
                                 + aw[dr][dc][2]*c10.x + aw[dr][dc][3]*c11.x;
                        float f2 = aw[dr][dc][0]*c00.y + aw[dr][dc][1]*c01.y
                                 + aw[dr][dc][2]*c10.y + aw[dr][dc][3]*c11.y;
                        acc1[dr][dc] += P1[dr+i][dc+j] * f1;
                        acc2[dr][dc] += P2[dr+i][dc+j] * f2;
                    }
                }
            }
        }

        float g00 = acc1[0][0]*acc2[0][0], g01 = acc1[0][1]*acc2[0][1];
        float g10 = acc1[1][0]*acc2[1][0], g11 = acc1[1][1]*acc2[1][1];
        unsigned* gp = g32 + (size_t)(b*32 + cp) * 32768 + h0*128 + (w0 >> 1);
        gp[0]   = pkf(g00, g01);
        gp[128] = pkf(g10, g11);

        float s = g00 + g01 + g10 + g11;
        #pragma unroll
        for (int off = 32; off >= 1; off >>= 1) s += __shfl_xor(s, off, 64);
        if (lane == 0) atomicAdd(&sums[b*32 + cp], s);
    }
}

// ---------------- k_sca ----------------
__global__ void k_sca(float* __restrict__ wsf)
{
    int t = threadIdx.x;            // 128
    int b = t >> 5, o = t & 31;
    float acc = wsf[OBS + o];
    #pragma unroll
    for (int ch = 0; ch < C_; ++ch)
        acc += wsf[OWS + o*C_ + ch] * (wsf[OSUMS + b*C_ + ch] * (1.f/(float)P_));
    wsf[OSVEC + b*C_ + o] = acc;
}

// ---------------- k_tail: 2 px/thread, bf16-packed LDS weights ----------------
__global__ __launch_bounds__(256, 2) void k_tail(const void* __restrict__ inp_,
        const unsigned* __restrict__ g32, const float* __restrict__ wsf,
        const unsigned* __restrict__ wsu, void* __restrict__ out_,
        const int* __restrict__ flag)
{
    __shared__ unsigned LP3[512], LP4[1024], LP5[512];
    __shared__ float LV[288];   // b3|b4(64)|b5|n2w|n2b|beta|gamma|sv

    int gt = blockIdx.x * 256 + threadIdx.x;   // 512 blocks
    int b = gt >> 15;
    int po = (gt & 32767) * 2;

    for (int i = threadIdx.x; i < 512; i += 256) { LP3[i] = wsu[OPK3u + i]; LP5[i] = wsu[OPK5u + i]; }
    for (int i = threadIdx.x; i < 1024; i += 256) LP4[i] = wsu[OPK4u + i];
    if (threadIdx.x < 32) {
        int t = threadIdx.x;
        LV[t]       = wsf[OB3 + t];
        LV[96 + t]  = wsf[OB5 + t];
        LV[128 + t] = wsf[ON2W + t];
        LV[160 + t] = wsf[ON2B + t];
        LV[192 + t] = wsf[OBETA + t];
        LV[224 + t] = wsf[OGAMMA + t];
        LV[256 + t] = wsf[OSVEC + b*32 + t];
    }
    if (threadIdx.x >= 32 && threadIdx.x < 96) LV[threadIdx.x] = wsf[OB4 + threadIdx.x - 32];
    __syncthreads();

    bool isf = (*flag == 0);
    float x0[32], x1[32];
    #pragma unroll
    for (int ch = 0; ch < 32; ++ch) {
        unsigned gu = g32[(size_t)(b*32 + ch) * 32768 + (po >> 1)];
        float sv = LV[256 + ch];
        x0[ch] = lo16f(gu) * sv;
        x1[ch] = hi16f(gu) * sv;
    }

    float y0[32], y1[32];
    #pragma unroll 2
    for (int o = 0; o < 32; ++o) {
        float a0 = LV[o], a1 = a0;
        const uint4* wr = (const uint4*)&LP3[o*16];
        #pragma unroll
        for (int k = 0; k < 4; ++k) {
            uint4 u = wr[k];
            int c = k*8;
            a0 += x0[c]*lo16f(u.x) + x0[c+1]*hi16f(u.x) + x0[c+2]*lo16f(u.y) + x0[c+3]*hi16f(u.y)
                + x0[c+4]*lo16f(u.z) + x0[c+5]*hi16f(u.z) + x0[c+6]*lo16f(u.w) + x0[c+7]*hi16f(u.w);
            a1 += x1[c]*lo16f(u.x) + x1[c+1]*hi16f(u.x) + x1[c+2]*lo16f(u.y) + x1[c+3]*hi16f(u.y)
                + x1[c+4]*lo16f(u.z) + x1[c+5]*hi16f(u.z) + x1[c+6]*lo16f(u.w) + x1[c+7]*hi16f(u.w);
        }
        float i0, i1;
        if (isf) {
            float2 iv = *(const float2*)((const float*)inp_ + (size_t)(b*C_ + o)*P_ + po);
            i0 = iv.x; i1 = iv.y;
        } else {
            unsigned ui = *(const unsigned*)((const unsigned short*)inp_ + (size_t)(b*C_ + o)*P_ + po);
            i0 = lo16f(ui); i1 = hi16f(ui);
        }
        float bt = LV[192 + o];
        y0[o] = i0 + a0*bt;
        y1[o] = i1 + a1*bt;
    }

    float m0 = 0.f, m1 = 0.f;
    #pragma unroll
    for (int ch = 0; ch < 32; ++ch) { m0 += y0[ch]; m1 += y1[ch]; }
    m0 *= (1.f/32); m1 *= (1.f/32);
    float v0 = 0.f, v1 = 0.f;
    #pragma unroll
    for (int ch = 0; ch < 32; ++ch) {
        float d0 = y0[ch]-m0, d1 = y1[ch]-m1;
        v0 += d0*d0; v1 += d1*d1;
    }
    float iv0 = rsqrtf(v0*(1.f/32) + 1e-6f), iv1 = rsqrtf(v1*(1.f/32) + 1e-6f);
    float yn0[32], yn1[32];
    #pragma unroll
    for (int ch = 0; ch < 32; ++ch) {
        float g = LV[128+ch], bb = LV[160+ch];
        yn0[ch] = (y0[ch]-m0)*iv0*g + bb;
        yn1[ch] = (y1[ch]-m1)*iv1*g + bb;
    }

    float u0[32], u1[32];
    #pragma unroll 2
    for (int o = 0; o < 32; ++o) {
        float A0 = LV[32+o], B0 = LV[64+o], A1 = A0, B1 = B0;
        const uint4* wa = (const uint4*)&LP4[o*16];
        const uint4* wb = (const uint4*)&LP4[(o+32)*16];
        #pragma unroll
        for (int k = 0; k < 4; ++k) {
            uint4 ua = wa[k], ub = wb[k];
            int c = k*8;
            A0 += yn0[c]*lo16f(ua.x) + yn0[c+1]*hi16f(ua.x) + yn0[c+2]*lo16f(ua.y) + yn0[c+3]*hi16f(ua.y)
                + yn0[c+4]*lo16f(ua.z) + yn0[c+5]*hi16f(ua.z) + yn0[c+6]*lo16f(ua.w) + yn0[c+7]*hi16f(ua.w);
            A1 += yn1[c]*lo16f(ua.x) + yn1[c+1]*hi16f(ua.x) + yn1[c+2]*lo16f(ua.y) + yn1[c+3]*hi16f(ua.y)
                + yn1[c+4]*lo16f(ua.z) + yn1[c+5]*hi16f(ua.z) + yn1[c+6]*lo16f(ua.w) + yn1[c+7]*hi16f(ua.w);
            B0 += yn0[c]*lo16f(ub.x) + yn0[c+1]*hi16f(ub.x) + yn0[c+2]*lo16f(ub.y) + yn0[c+3]*hi16f(ub.y)
                + yn0[c+4]*lo16f(ub.z) + yn0[c+5]*hi16f(ub.z) + yn0[c+6]*lo16f(ub.w) + yn0[c+7]*hi16f(ub.w);
            B1 += yn1[c]*lo16f(ub.x) + yn1[c+1]*hi16f(ub.x) + yn1[c+2]*lo16f(ub.y) + yn1[c+3]*hi16f(ub.y)
                + yn1[c+4]*lo16f(ub.z) + yn1[c+5]*hi16f(ub.z) + yn1[c+6]*lo16f(ub.w) + yn1[c+7]*hi16f(ub.w);
        }
        u0[o] = A0*B0;
        u1[o] = A1*B1;
    }

    #pragma unroll 2
    for (int o = 0; o < 32; ++o) {
        float a0 = LV[96+o], a1 = a0;
        const uint4* wr = (const uint4*)&LP5[o*16];
        #pragma unroll
        for (int k = 0; k < 4; ++k) {
            uint4 u = wr[k];
            int c = k*8;
            a0 += u0[c]*lo16f(u.x) + u0[c+1]*hi16f(u.x) + u0[c+2]*lo16f(u.y) + u0[c+3]*hi16f(u.y)
                + u0[c+4]*lo16f(u.z) + u0[c+5]*hi16f(u.z) + u0[c+6]*lo16f(u.w) + u0[c+7]*hi16f(u.w);
            a1 += u1[c]*lo16f(u.x) + u1[c+1]*hi16f(u.x) + u1[c+2]*lo16f(u.y) + u1[c+3]*hi16f(u.y)
                + u1[c+4]*lo16f(u.z) + u1[c+5]*hi16f(u.z) + u1[c+6]*lo16f(u.w) + u1[c+7]*hi16f(u.w);
        }
        float gm = LV[224+o];
        float o0 = y0[o] + a0*gm, o1 = y1[o] + a1*gm;
        if (isf) {
            *(float2*)((float*)out_ + (size_t)(b*C_ + o)*P_ + po) = make_float2(o0, o1);
        } else {
            *((unsigned*)out_ + ((size_t)(b*C_ + o)*P_ + po) / 2) = pkf(o0, o1);
        }
    }
}

extern "C" void kernel_launch(void* const* d_in, const int* in_sizes, int n_in,
                              void* d_out, int out_size, void* d_ws, size_t ws_size,
                              hipStream_t stream)
{
    float* wsf = (float*)d_ws;
    unsigned* wsu = (unsigned*)d_ws;
    char* wsb = (char*)d_ws;
    float* cwf = (float*)(wsb + CWF_BOFF);
    unsigned* t1u = (unsigned*)(wsb + T1_BOFF);
    unsigned* g32 = (unsigned*)(wsb + G_BOFF);
    int* flag = (int*)(wsf + OFLAG);

    k_setup<<<1024, 256, 0, stream>>>(
        (const unsigned short*)d_in[0], d_in[1],
        d_in[2], d_in[3], d_in[4], d_in[5], d_in[6], d_in[7], d_in[8], d_in[9],
        d_in[10], d_in[11], d_in[12], d_in[13], d_in[14], d_in[15], d_in[16], d_in[17],
        wsf, wsu, cwf, t1u, flag);

    k_ln1<<<256, 256, 0, stream>>>(d_in[0], wsf, t1u, flag);

    k_ddf<<<1024, 256, 0, stream>>>(t1u, cwf, (const float*)d_in[1], g32,
                                    wsf + OSUMS, flag);

    k_sca<<<1, 128, 0, stream>>>(wsf);

    k_tail<<<512, 256, 0, stream>>>(d_in[0], g32, wsf, wsu, d_out, flag);
}